// Round 1
// baseline (111.138 us; speedup 1.0000x reference)
//
#include <hip/hip_runtime.h>

// Problem dims (fixed by reference): B=16, N=1024, D=512, DIRECTIONS=2
#define NB 16
#define NN 1024
#define ND 512

typedef __attribute__((ext_vector_type(8))) short short8;   // 8 x bf16 (4 VGPRs)
typedef __attribute__((ext_vector_type(4))) float f32x4;

typedef const __attribute__((address_space(1))) void* gptr1;
typedef __attribute__((address_space(3))) void* lptr3;

static __device__ __forceinline__ unsigned f2bf(float f) {
  union { float f; unsigned u; } v; v.f = f;
  unsigned r = v.u + 0x7FFFu + ((v.u >> 16) & 1u);   // RNE
  return r >> 16;
}

// ---------------- P1: per-row class counts -> inverse weights ----------------
__global__ void k_count(const int* __restrict__ adj, float* __restrict__ invc) {
  int row = blockIdx.x * 4 + (threadIdx.x >> 6);   // [0, NB*NN)
  int lane = threadIdx.x & 63;
  const int4* p = (const int4*)(adj + (size_t)row * NN);
  int c1 = 0, c2 = 0;
#pragma unroll
  for (int i = 0; i < 4; ++i) {
    int4 v = p[lane + 64 * i];
    c1 += (v.x == 1) + (v.y == 1) + (v.z == 1) + (v.w == 1);
    c2 += (v.x == 2) + (v.y == 2) + (v.z == 2) + (v.w == 2);
  }
#pragma unroll
  for (int o = 32; o; o >>= 1) { c1 += __shfl_xor(c1, o); c2 += __shfl_xor(c2, o); }
  if (lane == 0) {
    invc[row * 2 + 0] = 1.0f / ((float)c1 + 1e-13f);
    invc[row * 2 + 1] = 1.0f / ((float)c2 + 1e-13f);
  }
}

// ------------- P2: transpose + f32->bf16 cast: hid -> hidT, W -> WT ----------
// src f32 [R=1024][C=512] -> dst bf16 [C=512][R=1024]
__global__ void k_transpose_cvt(const float* __restrict__ hid, const float* __restrict__ W,
                                unsigned short* __restrict__ hidT, unsigned short* __restrict__ WT) {
  __shared__ float t[64][65];
  int z = blockIdx.z;
  const float* src; unsigned short* dst;
  if (z < NB) { src = hid + (size_t)z * NN * ND; dst = hidT + (size_t)z * ND * NN; }
  else        { src = W;                          dst = WT; }
  int r0 = blockIdx.x * 64;   // over R=1024
  int c0 = blockIdx.y * 64;   // over C=512
  int tid = threadIdx.x;
#pragma unroll
  for (int i = 0; i < 4; ++i) {
    int f = i * 256 + tid;
    int r = f >> 4, cq = f & 15;
    float4 v = *(const float4*)(src + (size_t)(r0 + r) * ND + c0 + cq * 4);
    t[r][cq * 4 + 0] = v.x; t[r][cq * 4 + 1] = v.y;
    t[r][cq * 4 + 2] = v.z; t[r][cq * 4 + 3] = v.w;
  }
  __syncthreads();
#pragma unroll
  for (int i = 0; i < 8; ++i) {
    int f = i * 256 + tid;
    int oc = f >> 5;            // 0..63 output row (C dim)
    int on = (f & 31) * 2;      // 0..62 output col (R dim), pair
    unsigned lo = f2bf(t[on][oc]), hi = f2bf(t[on + 1][oc]);
    *(unsigned*)(dst + (size_t)(c0 + oc) * NN + r0 + on) = lo | (hi << 16);
  }
}

// -------- P3: aggregation GEMM: Y[:, j*512+d] = inv_j[n] * (mask_j @ hid) ----
// Per batch: M=N=1024 rows n, Ncols=512 (d), K=1024 (m).  BM=128 BN=128 BK=64.
__global__ __launch_bounds__(256, 2) void k_agg(
    const int* __restrict__ adj, const unsigned short* __restrict__ hidT,
    const float* __restrict__ invc, unsigned short* __restrict__ Y) {
  __shared__ __align__(16) char smem[49152];
  char* A1 = smem;                // mask1 tile [128][64] bf16, 16B-slot XOR swizzle
  char* A2 = smem + 16384;        // mask2 tile
  char* Bt = smem + 32768;        // hidT tile [128 cols d][64 k] bf16, swizzled

  int phys = blockIdx.x;                       // 512 blocks, 512%8==0 -> simple XCD swizzle
  int logical = (phys & 7) * 64 + (phys >> 3);
  int b  = logical >> 5;
  int rem = logical & 31;
  int mt = rem >> 2, nt = rem & 3;
  int m0 = mt * 128, n0 = nt * 128;

  int tid = threadIdx.x;
  int lane = tid & 63, wid = tid >> 6;
  int wr = wid >> 1, wc = wid & 1;

  const int* adjb = adj + (size_t)b * NN * NN;
  const unsigned short* hTb = hidT + (size_t)b * ND * NN;

  f32x4 acc1[4][4], acc2[4][4];
  f32x4 zero = {0.f, 0.f, 0.f, 0.f};
#pragma unroll
  for (int i = 0; i < 4; ++i)
#pragma unroll
    for (int j = 0; j < 4; ++j) { acc1[i][j] = zero; acc2[i][j] = zero; }

  for (int kt = 0; kt < 16; ++kt) {
    int k0 = kt * 64;
    __syncthreads();
    // ---- stage A: adj -> two bf16 mask tiles (reg-staged, swizzled ds_write)
#pragma unroll
    for (int it = 0; it < 8; ++it) {
      int f = it * 256 + tid;
      int row = f >> 4, colq = f & 15;           // 16 int4 per 64-elem row
      int4 v = *(const int4*)(adjb + (size_t)(m0 + row) * NN + k0 + colq * 4);
      unsigned m1a = (v.x == 1 ? 0x3F80u : 0u) | (v.y == 1 ? 0x3F800000u : 0u);
      unsigned m1b = (v.z == 1 ? 0x3F80u : 0u) | (v.w == 1 ? 0x3F800000u : 0u);
      unsigned m2a = (v.x == 2 ? 0x3F80u : 0u) | (v.y == 2 ? 0x3F800000u : 0u);
      unsigned m2b = (v.z == 2 ? 0x3F80u : 0u) | (v.w == 2 ? 0x3F800000u : 0u);
      int addr = row * 128 + (((colq >> 1) ^ (row & 7)) * 16) + (colq & 1) * 8;
      *(uint2*)(A1 + addr) = make_uint2(m1a, m1b);
      *(uint2*)(A2 + addr) = make_uint2(m2a, m2b);
    }
    // ---- stage B: hidT rows via global_load_lds (linear LDS dest, pre-swizzled src)
#pragma unroll
    for (int i = 0; i < 4; ++i) {
      int q = wid * 4 + i;                 // 16 calls x 1KB
      int c = q * 8 + (lane >> 3);         // LDS row (d index)
      int s = (lane & 7) ^ (c & 7);        // source slot for this linear dest slot
      const unsigned short* src = hTb + (size_t)(n0 + c) * NN + k0 + s * 8;
      __builtin_amdgcn_global_load_lds((gptr1)src, (lptr3)(Bt + q * 1024), 16, 0, 0);
    }
    __syncthreads();
    // ---- compute: 2 k-substeps of K=32, 4x4 fragments per wave, both masks
#pragma unroll
    for (int ks = 0; ks < 2; ++ks) {
      short8 a1[4], a2[4], bf[4];
#pragma unroll
      for (int mi = 0; mi < 4; ++mi) {
        int row = wr * 64 + mi * 16 + (lane & 15);
        int slot = (ks * 4 + (lane >> 4)) ^ (row & 7);
        a1[mi] = *(const short8*)(A1 + row * 128 + slot * 16);
        a2[mi] = *(const short8*)(A2 + row * 128 + slot * 16);
      }
#pragma unroll
      for (int nj = 0; nj < 4; ++nj) {
        int col = wc * 64 + nj * 16 + (lane & 15);
        int slot = (ks * 4 + (lane >> 4)) ^ (col & 7);
        bf[nj] = *(const short8*)(Bt + col * 128 + slot * 16);
      }
#pragma unroll
      for (int mi = 0; mi < 4; ++mi)
#pragma unroll
        for (int nj = 0; nj < 4; ++nj) {
          acc1[mi][nj] = __builtin_amdgcn_mfma_f32_16x16x32_bf16(a1[mi], bf[nj], acc1[mi][nj], 0, 0, 0);
          acc2[mi][nj] = __builtin_amdgcn_mfma_f32_16x16x32_bf16(a2[mi], bf[nj], acc2[mi][nj], 0, 0, 0);
        }
    }
  }
  // ---- epilogue: scale by inv count, cast bf16, store Y[b][n][j*512+d]
  unsigned short* Yb = Y + (size_t)b * NN * (2 * ND);
#pragma unroll
  for (int mi = 0; mi < 4; ++mi) {
#pragma unroll
    for (int rr = 0; rr < 4; ++rr) {
      int grow = m0 + wr * 64 + mi * 16 + (lane >> 4) * 4 + rr;
      float i1 = invc[((size_t)b * NN + grow) * 2 + 0];
      float i2 = invc[((size_t)b * NN + grow) * 2 + 1];
#pragma unroll
      for (int nj = 0; nj < 4; ++nj) {
        int col = n0 + wc * 64 + nj * 16 + (lane & 15);
        Yb[(size_t)grow * 1024 + col]       = (unsigned short)f2bf(acc1[mi][nj][rr] * i1);
        Yb[(size_t)grow * 1024 + 512 + col] = (unsigned short)f2bf(acc2[mi][nj][rr] * i2);
      }
    }
  }
}

// -------- P4: out = relu(Y @ W + b) + hid  (pre-LN f32 written to d_out) ----
// M=16384, K=1024, Ncols=512.  BM=128 BN=128 BK=64.
__global__ __launch_bounds__(256, 2) void k_out(
    const unsigned short* __restrict__ Y, const unsigned short* __restrict__ WT,
    const float* __restrict__ bias, const float* __restrict__ hid,
    float* __restrict__ out) {
  __shared__ __align__(16) char smem[32768];
  char* At = smem;             // Y tile [128 rows][64 k]
  char* Bt = smem + 16384;     // WT tile [128 cols][64 k]

  int phys = blockIdx.x;
  int logical = (phys & 7) * 64 + (phys >> 3);
  int mt = logical >> 2, nt = logical & 3;
  int m0 = mt * 128, n0 = nt * 128;

  int tid = threadIdx.x, lane = tid & 63, wid = tid >> 6;
  int wr = wid >> 1, wc = wid & 1;

  f32x4 acc[4][4];
  f32x4 zero = {0.f, 0.f, 0.f, 0.f};
#pragma unroll
  for (int i = 0; i < 4; ++i)
#pragma unroll
    for (int j = 0; j < 4; ++j) acc[i][j] = zero;

  for (int kt = 0; kt < 16; ++kt) {
    int k0 = kt * 64;
    __syncthreads();
#pragma unroll
    for (int i = 0; i < 4; ++i) {
      int q = wid * 4 + i;
      int r = q * 8 + (lane >> 3);
      int s = (lane & 7) ^ (r & 7);
      const unsigned short* src = Y + (size_t)(m0 + r) * 1024 + k0 + s * 8;
      __builtin_amdgcn_global_load_lds((gptr1)src, (lptr3)(At + q * 1024), 16, 0, 0);
    }
#pragma unroll
    for (int i = 0; i < 4; ++i) {
      int q = wid * 4 + i;
      int c = q * 8 + (lane >> 3);
      int s = (lane & 7) ^ (c & 7);
      const unsigned short* src = WT + (size_t)(n0 + c) * 1024 + k0 + s * 8;
      __builtin_amdgcn_global_load_lds((gptr1)src, (lptr3)(Bt + q * 1024), 16, 0, 0);
    }
    __syncthreads();
#pragma unroll
    for (int ks = 0; ks < 2; ++ks) {
      short8 af[4], bf[4];
#pragma unroll
      for (int mi = 0; mi < 4; ++mi) {
        int row = wr * 64 + mi * 16 + (lane & 15);
        int slot = (ks * 4 + (lane >> 4)) ^ (row & 7);
        af[mi] = *(const short8*)(At + row * 128 + slot * 16);
      }
#pragma unroll
      for (int nj = 0; nj < 4; ++nj) {
        int col = wc * 64 + nj * 16 + (lane & 15);
        int slot = (ks * 4 + (lane >> 4)) ^ (col & 7);
        bf[nj] = *(const short8*)(Bt + col * 128 + slot * 16);
      }
#pragma unroll
      for (int mi = 0; mi < 4; ++mi)
#pragma unroll
        for (int nj = 0; nj < 4; ++nj)
          acc[mi][nj] = __builtin_amdgcn_mfma_f32_16x16x32_bf16(af[mi], bf[nj], acc[mi][nj], 0, 0, 0);
    }
  }
#pragma unroll
  for (int mi = 0; mi < 4; ++mi) {
#pragma unroll
    for (int rr = 0; rr < 4; ++rr) {
      int grow = m0 + wr * 64 + mi * 16 + (lane >> 4) * 4 + rr;
#pragma unroll
      for (int nj = 0; nj < 4; ++nj) {
        int col = n0 + wc * 64 + nj * 16 + (lane & 15);
        float v = acc[mi][nj][rr] + bias[col];
        v = fmaxf(v, 0.f);
        v += hid[(size_t)grow * ND + col];
        out[(size_t)grow * ND + col] = v;
      }
    }
  }
}

// ---------------- P5: in-place rowwise LayerNorm on d_out --------------------
__global__ void k_ln(float* __restrict__ out, const float* __restrict__ gamma,
                     const float* __restrict__ beta) {
  int row = blockIdx.x * 4 + (threadIdx.x >> 6);
  int lane = threadIdx.x & 63;
  float* p = out + (size_t)row * ND;
  float4 x0 = *(const float4*)(p + lane * 4);
  float4 x1 = *(const float4*)(p + 256 + lane * 4);
  float s = x0.x + x0.y + x0.z + x0.w + x1.x + x1.y + x1.z + x1.w;
#pragma unroll
  for (int o = 32; o; o >>= 1) s += __shfl_xor(s, o);
  float mu = s * (1.0f / 512.0f);
  float d0x = x0.x - mu, d0y = x0.y - mu, d0z = x0.z - mu, d0w = x0.w - mu;
  float d1x = x1.x - mu, d1y = x1.y - mu, d1z = x1.z - mu, d1w = x1.w - mu;
  float v = d0x * d0x + d0y * d0y + d0z * d0z + d0w * d0w
          + d1x * d1x + d1y * d1y + d1z * d1z + d1w * d1w;
#pragma unroll
  for (int o = 32; o; o >>= 1) v += __shfl_xor(v, o);
  float rs = rsqrtf(v * (1.0f / 512.0f) + 1e-5f);
  float4 g0 = *(const float4*)(gamma + lane * 4);
  float4 g1 = *(const float4*)(gamma + 256 + lane * 4);
  float4 b0 = *(const float4*)(beta + lane * 4);
  float4 b1 = *(const float4*)(beta + 256 + lane * 4);
  float4 y0, y1;
  y0.x = d0x * rs * g0.x + b0.x; y0.y = d0y * rs * g0.y + b0.y;
  y0.z = d0z * rs * g0.z + b0.z; y0.w = d0w * rs * g0.w + b0.w;
  y1.x = d1x * rs * g1.x + b1.x; y1.y = d1y * rs * g1.y + b1.y;
  y1.z = d1z * rs * g1.z + b1.z; y1.w = d1w * rs * g1.w + b1.w;
  *(float4*)(p + lane * 4) = y0;
  *(float4*)(p + 256 + lane * 4) = y1;
}

extern "C" void kernel_launch(void* const* d_in, const int* in_sizes, int n_in,
                              void* d_out, int out_size, void* d_ws, size_t ws_size,
                              hipStream_t stream) {
  (void)in_sizes; (void)n_in; (void)out_size; (void)ws_size;
  const int*   adj   = (const int*)d_in[0];
  const float* hid   = (const float*)d_in[1];
  const float* W     = (const float*)d_in[2];
  const float* bias  = (const float*)d_in[3];
  const float* gamma = (const float*)d_in[4];
  const float* beta  = (const float*)d_in[5];
  float* out = (float*)d_out;

  char* ws = (char*)d_ws;
  float*          invc = (float*)ws;                              // 16384*2*4   = 131072 B
  unsigned short* hidT = (unsigned short*)(ws + 131072);          // 16*512*1024*2 = 16 MiB
  unsigned short* WT   = (unsigned short*)(ws + 16908288);        // 512*1024*2  = 1 MiB
  unsigned short* Y    = (unsigned short*)(ws + 17956864);        // 16*1024*1024*2 = 32 MiB
                                                                  // total ~49.2 MiB
  k_count<<<4096, 256, 0, stream>>>(adj, invc);
  k_transpose_cvt<<<dim3(16, 8, 17), 256, 0, stream>>>(hid, W, hidT, WT);
  k_agg<<<512, 256, 0, stream>>>(adj, hidT, invc, Y);
  k_out<<<512, 256, 0, stream>>>(Y, WT, bias, hid, out);
  k_ln<<<4096, 256, 0, stream>>>(out, gamma, beta);
}